// Round 2
// baseline (2121.330 us; speedup 1.0000x reference)
//
#include <hip/hip_runtime.h>
#include <cstdint>
#include <cstddef>

#define N_TOK 2048
#define N_EXP 64
#define TOPK  8
#define DHID  2048
#define DFFN  768
#define CAP   512

typedef short s16x8 __attribute__((ext_vector_type(8)));
typedef float f32x4 __attribute__((ext_vector_type(4)));
typedef unsigned short u16x8 __attribute__((ext_vector_type(8)));

// fp32 -> bf16 round-to-nearest (half away)
__device__ __forceinline__ unsigned pk_bf2(float a, float b) {
    unsigned ua = __float_as_uint(a) + 0x8000u;
    unsigned ub = __float_as_uint(b) + 0x8000u;
    return (ua >> 16) | (ub & 0xffff0000u);
}
__device__ __forceinline__ unsigned short f2bf(float a) {
    return (unsigned short)((__float_as_uint(a) + 0x8000u) >> 16);
}
__device__ __forceinline__ float bf2f(unsigned short v) {
    return __uint_as_float(((unsigned)v) << 16);
}

// ---------------- zero counters only (combine path) ----------------
__global__ __launch_bounds__(64) void k_zero(int* __restrict__ counts) {
    counts[threadIdx.x] = 0;
}

// ---------------- init: zero out + counters (atomic fallback path) ----------------
__global__ __launch_bounds__(256) void k_init(float4* __restrict__ out4, int* __restrict__ counts) {
    int idx = blockIdx.x * 256 + threadIdx.x;
    const int total = (N_TOK * DHID) / 4;
    for (int i = idx; i < total; i += gridDim.x * 256)
        out4[i] = make_float4(0.f, 0.f, 0.f, 0.f);
    if (idx < N_EXP) counts[idx] = 0;
}

// ---------------- gating: fp32 logits, softmax, top-8, dispatch ----------------
__global__ __launch_bounds__(256) void k_gate(const float* __restrict__ x,
                                              const float* __restrict__ gw,
                                              int* __restrict__ counts,
                                              int* __restrict__ btok,
                                              float* __restrict__ bscore,
                                              int* __restrict__ pair_slot) {
    __shared__ __align__(16) float xs[4][DHID];   // 32 KB
    int t = threadIdx.x;
    int tok0 = blockIdx.x * 4;
    for (int r = 0; r < 4; ++r) {
        const float4* src = (const float4*)(x + (size_t)(tok0 + r) * DHID);
        float4* dst = (float4*)xs[r];
        for (int i = t; i < DHID / 4; i += 256) dst[i] = src[i];
    }
    __syncthreads();
    int w = t >> 6, lane = t & 63;
    int tok = tok0 + w;
    const float4* grow = (const float4*)(gw + (size_t)lane * DHID);
    const float4* xr = (const float4*)xs[w];
    float acc = 0.f;
    #pragma unroll 4
    for (int i = 0; i < DHID / 4; ++i) {
        float4 a = xr[i], b = grow[i];
        acc += a.x * b.x + a.y * b.y + a.z * b.z + a.w * b.w;
    }
    // softmax over 64 lanes (lane = expert)
    float m = acc;
    for (int o = 32; o > 0; o >>= 1) m = fmaxf(m, __shfl_xor(m, o));
    float ex = expf(acc - m);
    float sum = ex;
    for (int o = 32; o > 0; o >>= 1) sum += __shfl_xor(sum, o);
    float p = ex / sum;
    // iterative top-8 with lowest-index tiebreak (matches jax.lax.top_k)
    float pv = p;
    for (int k = 0; k < TOPK; ++k) {
        float mx = pv;
        for (int o = 32; o > 0; o >>= 1) mx = fmaxf(mx, __shfl_xor(mx, o));
        unsigned long long sel = __ballot(pv == mx);
        int who = __ffsll(sel) - 1;
        if (lane == who) {
            pv = -1.f;
            int pos = atomicAdd(&counts[lane], 1);
            int psv = -1;
            if (pos < CAP) {                       // capacity drop, like reference
                btok[lane * CAP + pos] = tok;
                bscore[lane * CAP + pos] = p;
                psv = lane * CAP + pos;
            }
            pair_slot[tok * TOPK + k] = psv;
        }
    }
}

// ---------------- gate/up GEMM + SwiGLU -> h (bf16) ----------------
// block = (f_chunk 64, expert). M-tile 128, BK 64. Register-prefetch pipeline:
// loads for iter k+1 are issued (to VGPRs) right after the staging barrier and
// fly across the MFMA phase; vmcnt wait lands at the next iter's convert.
__global__ __launch_bounds__(256, 2) void k_gateup(const float* __restrict__ x,
                                                   const float* __restrict__ wg,
                                                   const float* __restrict__ wu,
                                                   const int* __restrict__ counts,
                                                   const int* __restrict__ btok,
                                                   const float* __restrict__ bscore,
                                                   unsigned short* __restrict__ h) {
    int e = blockIdx.y;
    int f0 = blockIdx.x * 64;
    int cnt = counts[e]; cnt = cnt > CAP ? CAP : cnt;
    if (cnt == 0) return;

    __shared__ unsigned short Xs[128][72];  // +8 pad: conflict-free b128
    __shared__ unsigned short Gs[64][72];
    __shared__ unsigned short Us[64][72];
    __shared__ float Ss[128];
    __shared__ int   Ts[128];

    int t = threadIdx.x;
    int w = t >> 6, lane = t & 63;
    int wm = w & 1, wf = w >> 1;            // 2x2 wave tiling: M-half, F-half
    int row = lane & 15, quad = lane >> 4;
    int sr = t >> 1, sq = t & 1;            // X staging: 1 row / 2 threads
    int sr4 = t >> 2, sq4 = t & 3;          // W staging: 1 row / 4 threads

    const size_t wbase = ((size_t)e * DFFN + f0) * DHID;
    const float* gbase = wg + wbase + (size_t)sr4 * DHID;
    const float* ubase = wu + wbase + (size_t)sr4 * DHID;

    float4 pX[8], pG[4], pU[4];

    for (int m0 = 0; m0 < cnt; m0 += 128) {
        __syncthreads();
        if (t < 128) {
            int slot = m0 + t;
            if (slot < cnt) { Ts[t] = btok[e * CAP + slot]; Ss[t] = bscore[e * CAP + slot]; }
            else            { Ts[t] = -1;                   Ss[t] = 0.f; }
        }
        __syncthreads();
        int tokr = Ts[sr];
        const float4* xbase = (const float4*)(x + (size_t)(tokr < 0 ? 0 : tokr) * DHID + sq * 32);

        // prologue prefetch (k0 = 0)
        {
            if (tokr >= 0) {
                #pragma unroll
                for (int i = 0; i < 8; ++i) pX[i] = xbase[i];
            }
            const float4* gsrc = (const float4*)(gbase) + sq4 * 4;
            const float4* usrc = (const float4*)(ubase) + sq4 * 4;
            #pragma unroll
            for (int i = 0; i < 4; ++i) pG[i] = gsrc[i];
            #pragma unroll
            for (int i = 0; i < 4; ++i) pU[i] = usrc[i];
        }

        f32x4 accg[4][2], accu[4][2];
        #pragma unroll
        for (int mi = 0; mi < 4; ++mi)
            #pragma unroll
            for (int fi = 0; fi < 2; ++fi) {
                accg[mi][fi] = f32x4{0.f, 0.f, 0.f, 0.f};
                accu[mi][fi] = f32x4{0.f, 0.f, 0.f, 0.f};
            }

        for (int k0 = 0; k0 < DHID; k0 += 64) {
            // ---- convert prefetched regs -> LDS (vmcnt waits happen here)
            if (tokr >= 0) {
                #pragma unroll
                for (int i = 0; i < 4; ++i) {
                    float4 v0 = pX[2 * i], v1 = pX[2 * i + 1];
                    uint4 o;
                    o.x = pk_bf2(v0.x, v0.y); o.y = pk_bf2(v0.z, v0.w);
                    o.z = pk_bf2(v1.x, v1.y); o.w = pk_bf2(v1.z, v1.w);
                    *(uint4*)&Xs[sr][sq * 32 + i * 8] = o;
                }
            } else {
                uint4 z = make_uint4(0u, 0u, 0u, 0u);
                #pragma unroll
                for (int i = 0; i < 4; ++i) *(uint4*)&Xs[sr][sq * 32 + i * 8] = z;
            }
            #pragma unroll
            for (int i = 0; i < 2; ++i) {
                float4 v0 = pG[2 * i], v1 = pG[2 * i + 1];
                uint4 o;
                o.x = pk_bf2(v0.x, v0.y); o.y = pk_bf2(v0.z, v0.w);
                o.z = pk_bf2(v1.x, v1.y); o.w = pk_bf2(v1.z, v1.w);
                *(uint4*)&Gs[sr4][sq4 * 16 + i * 8] = o;
            }
            #pragma unroll
            for (int i = 0; i < 2; ++i) {
                float4 v0 = pU[2 * i], v1 = pU[2 * i + 1];
                uint4 o;
                o.x = pk_bf2(v0.x, v0.y); o.y = pk_bf2(v0.z, v0.w);
                o.z = pk_bf2(v1.x, v1.y); o.w = pk_bf2(v1.z, v1.w);
                *(uint4*)&Us[sr4][sq4 * 16 + i * 8] = o;
            }
            __syncthreads();
            // ---- issue next iter's loads (fly across the MFMA phase)
            int kn = k0 + 64;
            if (kn < DHID) {
                if (tokr >= 0) {
                    const float4* src = xbase + kn / 4;
                    #pragma unroll
                    for (int i = 0; i < 8; ++i) pX[i] = src[i];
                }
                const float4* gsrc = (const float4*)(gbase + kn) + sq4 * 4;
                const float4* usrc = (const float4*)(ubase + kn) + sq4 * 4;
                #pragma unroll
                for (int i = 0; i < 4; ++i) pG[i] = gsrc[i];
                #pragma unroll
                for (int i = 0; i < 4; ++i) pU[i] = usrc[i];
            }
            // ---- MFMA phase
            #pragma unroll
            for (int kf = 0; kf < 2; ++kf) {
                s16x8 a[4];
                #pragma unroll
                for (int mi = 0; mi < 4; ++mi)
                    a[mi] = *(const s16x8*)&Xs[wm * 64 + mi * 16 + row][kf * 32 + quad * 8];
                #pragma unroll
                for (int fi = 0; fi < 2; ++fi) {
                    s16x8 bg = *(const s16x8*)&Gs[wf * 32 + fi * 16 + row][kf * 32 + quad * 8];
                    s16x8 bu = *(const s16x8*)&Us[wf * 32 + fi * 16 + row][kf * 32 + quad * 8];
                    #pragma unroll
                    for (int mi = 0; mi < 4; ++mi) {
                        accg[mi][fi] = __builtin_amdgcn_mfma_f32_16x16x32_bf16(a[mi], bg, accg[mi][fi], 0, 0, 0);
                        accu[mi][fi] = __builtin_amdgcn_mfma_f32_16x16x32_bf16(a[mi], bu, accu[mi][fi], 0, 0, 0);
                    }
                }
            }
            __syncthreads();
        }
        // ---- epilogue: h = silu(g)*u*score, bf16 (pad rows -> 0)
        #pragma unroll
        for (int mi = 0; mi < 4; ++mi)
            #pragma unroll
            for (int fi = 0; fi < 2; ++fi)
                #pragma unroll
                for (int r = 0; r < 4; ++r) {
                    int sl = wm * 64 + mi * 16 + quad * 4 + r;
                    float g = accg[mi][fi][r], u = accu[mi][fi][r];
                    float hv = g * (1.f / (1.f + __expf(-g))) * u * Ss[sl];
                    size_t slot = (size_t)(m0 + sl);
                    h[((size_t)e * CAP + slot) * DFFN + f0 + wf * 32 + fi * 16 + row] = f2bf(hv);
                }
    }
}

// ---------------- down GEMM; USE_Y: write slot-rows to y (no atomics),
// else atomicAdd scatter into out (fallback when ws too small) ----------------
template <bool USE_Y>
__global__ __launch_bounds__(256, 2) void k_down(const unsigned short* __restrict__ h,
                                                 const float* __restrict__ wd,
                                                 const int* __restrict__ counts,
                                                 const int* __restrict__ btok,
                                                 unsigned short* __restrict__ y,
                                                 float* __restrict__ out) {
    int e = blockIdx.y;
    int d0 = blockIdx.x * 64;
    int cnt = counts[e]; cnt = cnt > CAP ? CAP : cnt;
    if (cnt == 0) return;

    __shared__ unsigned short Hs[128][72];
    __shared__ unsigned short Ws[64][72];
    __shared__ int Ts[128];

    int t = threadIdx.x;
    int w = t >> 6, lane = t & 63;
    int wm = w & 1, wdh = w >> 1;
    int row = lane & 15, quad = lane >> 4;
    int sr = t >> 1, sq = t & 1;
    int sr4 = t >> 2, sq4 = t & 3;

    const size_t wbase = ((size_t)e * DHID + d0) * DFFN;
    const float* dbase = wd + wbase + (size_t)sr4 * DFFN;

    uint4  pH[4];
    float4 pW[4];

    for (int m0 = 0; m0 < cnt; m0 += 128) {
        __syncthreads();
        if (USE_Y) {
            // slot-indexed output: no token map needed
        } else if (t < 128) {
            int slot = m0 + t;
            Ts[t] = (slot < cnt) ? btok[e * CAP + slot] : -1;
        }
        __syncthreads();

        const uint4* hbase = (const uint4*)(h + ((size_t)e * CAP + (m0 + sr)) * DFFN + sq * 32);
        // prologue prefetch (k0 = 0)
        {
            #pragma unroll
            for (int i = 0; i < 4; ++i) pH[i] = hbase[i];
            const float4* dsrc = (const float4*)(dbase) + sq4 * 4;
            #pragma unroll
            for (int i = 0; i < 4; ++i) pW[i] = dsrc[i];
        }

        f32x4 acc[4][2];
        #pragma unroll
        for (int mi = 0; mi < 4; ++mi)
            #pragma unroll
            for (int di = 0; di < 2; ++di)
                acc[mi][di] = f32x4{0.f, 0.f, 0.f, 0.f};

        for (int k0 = 0; k0 < DFFN; k0 += 64) {
            // ---- stage from prefetch regs
            #pragma unroll
            for (int i = 0; i < 4; ++i)
                *(uint4*)&Hs[sr][sq * 32 + i * 8] = pH[i];
            #pragma unroll
            for (int i = 0; i < 2; ++i) {
                float4 v0 = pW[2 * i], v1 = pW[2 * i + 1];
                uint4 o;
                o.x = pk_bf2(v0.x, v0.y); o.y = pk_bf2(v0.z, v0.w);
                o.z = pk_bf2(v1.x, v1.y); o.w = pk_bf2(v1.z, v1.w);
                *(uint4*)&Ws[sr4][sq4 * 16 + i * 8] = o;
            }
            __syncthreads();
            // ---- issue next iter's loads
            int kn = k0 + 64;
            if (kn < DFFN) {
                const uint4* hsrc = hbase + kn / 8;
                #pragma unroll
                for (int i = 0; i < 4; ++i) pH[i] = hsrc[i];
                const float4* dsrc = (const float4*)(dbase + kn) + sq4 * 4;
                #pragma unroll
                for (int i = 0; i < 4; ++i) pW[i] = dsrc[i];
            }
            // ---- MFMA phase
            #pragma unroll
            for (int kf = 0; kf < 2; ++kf) {
                s16x8 a[4];
                #pragma unroll
                for (int mi = 0; mi < 4; ++mi)
                    a[mi] = *(const s16x8*)&Hs[wm * 64 + mi * 16 + row][kf * 32 + quad * 8];
                #pragma unroll
                for (int di = 0; di < 2; ++di) {
                    s16x8 b = *(const s16x8*)&Ws[wdh * 32 + di * 16 + row][kf * 32 + quad * 8];
                    #pragma unroll
                    for (int mi = 0; mi < 4; ++mi)
                        acc[mi][di] = __builtin_amdgcn_mfma_f32_16x16x32_bf16(a[mi], b, acc[mi][di], 0, 0, 0);
                }
            }
            __syncthreads();
        }
        // ---- output
        if (USE_Y) {
            #pragma unroll
            for (int mi = 0; mi < 4; ++mi)
                #pragma unroll
                for (int di = 0; di < 2; ++di)
                    #pragma unroll
                    for (int r = 0; r < 4; ++r) {
                        int sl = wm * 64 + mi * 16 + quad * 4 + r;
                        size_t slot = (size_t)e * CAP + (m0 + sl);
                        y[slot * DHID + d0 + wdh * 32 + di * 16 + row] = f2bf(acc[mi][di][r]);
                    }
        } else {
            #pragma unroll
            for (int mi = 0; mi < 4; ++mi)
                #pragma unroll
                for (int di = 0; di < 2; ++di)
                    #pragma unroll
                    for (int r = 0; r < 4; ++r) {
                        int sl = wm * 64 + mi * 16 + quad * 4 + r;
                        int tok = Ts[sl];
                        if (tok >= 0)
                            atomicAdd(out + (size_t)tok * DHID + d0 + wdh * 32 + di * 16 + row,
                                      acc[mi][di][r]);
                    }
        }
    }
}

// ---------------- combine: out[tok] = sum_k y[pair_slot[tok,k]] ----------------
__global__ __launch_bounds__(256) void k_combine(const unsigned short* __restrict__ y,
                                                 const int* __restrict__ pair_slot,
                                                 float* __restrict__ out) {
    int w = threadIdx.x >> 6, lane = threadIdx.x & 63;
    int tok = blockIdx.x * 4 + w;
    int slots[TOPK];
    #pragma unroll
    for (int k = 0; k < TOPK; ++k) slots[k] = pair_slot[tok * TOPK + k];
    for (int c0 = 0; c0 < DHID; c0 += 512) {
        int c = c0 + lane * 8;
        float acc[8] = {0.f, 0.f, 0.f, 0.f, 0.f, 0.f, 0.f, 0.f};
        #pragma unroll
        for (int k = 0; k < TOPK; ++k) {
            int s = slots[k];
            if (s >= 0) {
                u16x8 v = *(const u16x8*)(y + (size_t)s * DHID + c);
                #pragma unroll
                for (int j = 0; j < 8; ++j) acc[j] += bf2f(v[j]);
            }
        }
        float4 o0 = make_float4(acc[0], acc[1], acc[2], acc[3]);
        float4 o1 = make_float4(acc[4], acc[5], acc[6], acc[7]);
        *(float4*)(out + (size_t)tok * DHID + c)     = o0;
        *(float4*)(out + (size_t)tok * DHID + c + 4) = o1;
    }
}

extern "C" void kernel_launch(void* const* d_in, const int* in_sizes, int n_in,
                              void* d_out, int out_size, void* d_ws, size_t ws_size,
                              hipStream_t stream) {
    const float* x  = (const float*)d_in[0];   // [1,2048,2048]
    const float* gw = (const float*)d_in[1];   // [64,2048]
    const float* wg = (const float*)d_in[2];   // [64,768,2048]
    const float* wu = (const float*)d_in[3];   // [64,768,2048]
    const float* wd = (const float*)d_in[4];   // [64,2048,768]
    float* out = (float*)d_out;

    char* ws = (char*)d_ws;
    int*   counts    = (int*)ws;                                // 64 ints
    int*   btok      = (int*)(ws + 4096);                       // [64][512]
    float* bscore    = (float*)(ws + 4096 + 131072);            // [64][512]
    int*   pair_slot = (int*)(ws + 4096 + 262144);              // [2048][8]
    unsigned short* h = (unsigned short*)(ws + (1 << 20));      // [64][512][768] bf16, 48 MB
    unsigned short* y = (unsigned short*)(ws + (1 << 20) + (size_t)N_EXP * CAP * DFFN * 2); // [64][512][2048] bf16, 128 MB

    const size_t need_big = (1 << 20) + (size_t)N_EXP * CAP * DFFN * 2
                                      + (size_t)N_EXP * CAP * DHID * 2;   // ~183.5 MB
    const bool bigws = ws_size >= need_big;   // constant per process -> graph-safe

    if (bigws) {
        k_zero<<<1, 64, 0, stream>>>(counts);
        k_gate<<<N_TOK / 4, 256, 0, stream>>>(x, gw, counts, btok, bscore, pair_slot);
        k_gateup<<<dim3(12, 64), 256, 0, stream>>>(x, wg, wu, counts, btok, bscore, h);
        k_down<true><<<dim3(32, 64), 256, 0, stream>>>(h, wd, counts, btok, y, out);
        k_combine<<<N_TOK / 4, 256, 0, stream>>>(y, pair_slot, out);
    } else {
        k_init<<<2048, 256, 0, stream>>>((float4*)out, counts);
        k_gate<<<N_TOK / 4, 256, 0, stream>>>(x, gw, counts, btok, bscore, pair_slot);
        k_gateup<<<dim3(12, 64), 256, 0, stream>>>(x, wg, wu, counts, btok, bscore, h);
        k_down<false><<<dim3(32, 64), 256, 0, stream>>>(h, wd, counts, btok, nullptr, out);
    }
}